// Round 7
// baseline (710.357 us; speedup 1.0000x reference)
//
#include <hip/hip_runtime.h>
#include <cstdint>
#include <cstddef>

// ---------- types / helpers ----------
typedef __attribute__((ext_vector_type(8))) short bf16x8;   // 8 bf16 (MFMA A/B frag)
typedef __attribute__((ext_vector_type(8))) int   v8i;      // 32 fp8 (f8f6f4 A/B frag)
typedef __attribute__((ext_vector_type(4))) float f32x4;    // MFMA C/D frag

__device__ __forceinline__ unsigned short f2bf(float x) {
    union { float f; unsigned u; } v; v.f = x;
    unsigned r = (v.u + 0x7fffu + ((v.u >> 16) & 1u)) >> 16;   // RNE, inputs finite
    return (unsigned short)r;
}
__device__ __forceinline__ unsigned short f2bf_trunc(float x) {
    union { float f; unsigned u; } v; v.f = x;
    return (unsigned short)(v.u >> 16);                        // truncation: 1 inst
}
__device__ __forceinline__ float bflo(unsigned u){ union{unsigned i;float f;}v; v.i = u << 16;        return v.f; }
__device__ __forceinline__ float bfhi(unsigned u){ union{unsigned i;float f;}v; v.i = u & 0xffff0000u; return v.f; }
__device__ __forceinline__ float frcp(float x){ return __builtin_amdgcn_rcpf(x); }

// lgkm-only barrier: keeps global loads in flight across the sync (CK pattern)
#define BARRIER_LGKM() asm volatile("s_waitcnt lgkmcnt(0)\n\ts_barrier" ::: "memory")

#define BB 64
#define TT 512
#define MM (BB*TT)     // 32768 rows (time-major: m = t*64 + b)
#define NG 1024        // 4H * 2 directions (permuted gate order)

#define NL2E  -1.442695f      // -log2(e): folded into i/f/o gate pre-acts
#define N2L2E -2.885390f      // -2*log2(e): folded into g gate pre-act

// Gate permutation (per direction): g2 = w*64 + tile*16 + uq*4 + gtype
//   unit = w*16 + tile*4 + uq ; orig row = gtype*128 + unit
__device__ __forceinline__ int perm_orig(int g2) {
    return (g2 & 3) * 128 + (g2 >> 6) * 16 + ((g2 >> 4) & 3) * 4 + ((g2 >> 2) & 3);
}

// ---------- prep: gather + permuted weight/bias convert + W_hh fp8 quantize ----------
__global__ void prep_kernel(
    const int* __restrict__ sentences, const float* __restrict__ emb,
    const float* __restrict__ w_ih_l0, const float* __restrict__ w_ih_l0r,
    const float* __restrict__ w_ih_l1, const float* __restrict__ w_ih_l1r,
    const float* __restrict__ w_hh_l0, const float* __restrict__ w_hh_l0r,
    const float* __restrict__ w_hh_l1, const float* __restrict__ w_hh_l1r,
    const float* __restrict__ b_ih_l0, const float* __restrict__ b_hh_l0,
    const float* __restrict__ b_ih_l0r, const float* __restrict__ b_hh_l0r,
    const float* __restrict__ b_ih_l1, const float* __restrict__ b_hh_l1,
    const float* __restrict__ b_ih_l1r, const float* __restrict__ b_hh_l1r,
    unsigned short* __restrict__ x0, unsigned short* __restrict__ W0c,
    unsigned short* __restrict__ W1c,
    int* __restrict__ Whh0q, int* __restrict__ Whh1q,
    float* __restrict__ bias0, float* __restrict__ bias1)
{
    int blk = blockIdx.x;
    if (blk < 4096) {                       // gather: 32768 x 128, time-major rows
        int t4 = blk * 256 + threadIdx.x;
        int e4 = t4 * 4; int m = e4 >> 7; int k = e4 & 127;
        int tt = m >> 6, b = m & 63;
        int s = sentences[b * 512 + tt];
        float4 v = *(const float4*)(emb + (size_t)s * 128 + k);
        *(ushort4*)(x0 + (size_t)m * 128 + k) =
            make_ushort4(f2bf(v.x), f2bf(v.y), f2bf(v.z), f2bf(v.w));
    } else if (blk < 4224) {                // W0c: 1024 x 128, permuted rows (bf16)
        int t4 = (blk - 4096) * 256 + threadIdx.x;
        int e4 = t4 * 4; int n = e4 >> 7; int k = e4 & 127;
        int dir = n >> 9; int orig = perm_orig(n & 511);
        const float* src = dir ? w_ih_l0r : w_ih_l0;
        float4 v = *(const float4*)(src + (size_t)orig * 128 + k);
        *(ushort4*)(W0c + (size_t)n * 128 + k) =
            make_ushort4(f2bf(v.x), f2bf(v.y), f2bf(v.z), f2bf(v.w));
    } else if (blk < 4480) {                // W1c: 1024 x 256, permuted rows (bf16)
        int t4 = (blk - 4224) * 256 + threadIdx.x;
        int e4 = t4 * 4; int n = e4 >> 8; int k = e4 & 255;
        int dir = n >> 9; int orig = perm_orig(n & 511);
        const float* src = dir ? w_ih_l1r : w_ih_l1;
        float4 v = *(const float4*)(src + (size_t)orig * 256 + k);
        *(ushort4*)(W1c + (size_t)n * 256 + k) =
            make_ushort4(f2bf(v.x), f2bf(v.y), f2bf(v.z), f2bf(v.w));
    } else if (blk < 4736) {                // W_hh fp8 (xscale), A-frag order, -log2e folded
        int lb = blk - 4480;                // 256 blocks: 128 per layer
        int layer = lb >> 7;
        int t4 = (lb & 127) * 256 + threadIdx.x;     // [0, 32768)
        int f  = t4 * 4;                              // byte index in 131072
        int j0   = f & 31;
        int lp   = (f >> 5) & 63;
        int quad = lp >> 4, r = lp & 15;
        int tb   = f >> 11;                           // 0..63
        int tile = tb & 3, w = (tb >> 2) & 7, dir = tb >> 5;
        int g2 = w * 64 + tile * 16 + r;
        int orig = perm_orig(g2);
        const float* src = layer ? (dir ? w_hh_l1r : w_hh_l1)
                                 : (dir ? w_hh_l0r : w_hh_l0);
        int k = quad * 32 + j0;
        // gtype = r & 3 ; g gate gets -2log2e, others -log2e; x64 for fp8 scale 2^-6
        float fac = ((r & 3) == 2) ? (N2L2E * 64.f) : (NL2E * 64.f);
        float4 v = *(const float4*)(src + (size_t)orig * 128 + k);
        int p = __builtin_amdgcn_cvt_pk_fp8_f32(v.x * fac, v.y * fac, 0, false);
        p = __builtin_amdgcn_cvt_pk_fp8_f32(v.z * fac, v.w * fac, p, true);
        (layer ? Whh1q : Whh0q)[f >> 2] = p;
    } else {                                // biases: 2048 values, permuted (unscaled)
        int t = (blk - 4736) * 256 + threadIdx.x;
        int n = t & 1023;
        int dir = n >> 9; int orig = perm_orig(n & 511);
        if (t < 1024)
            bias0[n] = dir ? (b_ih_l0r[orig] + b_hh_l0r[orig]) : (b_ih_l0[orig] + b_hh_l0[orig]);
        else
            bias1[n] = dir ? (b_ih_l1r[orig] + b_hh_l1r[orig]) : (b_ih_l1[orig] + b_hh_l1[orig]);
    }
}

// ---------- GEMM: xg[m][n] = (sum_k X[m][k]*W[n][k] + bias[n]) * gate_scale ----------
// Scan layout (ushort idx): pair*131072 + dir*65536 + bg*4096 + w*512 + thalf*256
//                           + (q*16 + b4*4 + d)*4   [d = tile, q = quad, b4 = b&3]
// -> per thread per j: i=0..3 contiguous 32B => 2 dwordx4 stores.
__global__ __launch_bounds__(256, 2) void gemm_xg(
    const unsigned short* __restrict__ W,   // [NG][K] permuted rows
    const unsigned short* __restrict__ X,   // [MM][K] time-major
    const float* __restrict__ bias,         // [NG] permuted
    unsigned short* __restrict__ xgS,       // scan layout, 64 MB
    int K)
{
    __shared__ unsigned short sW[128 * 32];
    __shared__ unsigned short sX[128 * 32];
    const int tid  = threadIdx.x;
    const int lane = tid & 63;
    const int wid  = tid >> 6;
    const int w_n  = wid & 1, w_m = wid >> 1;
    const int r16  = lane & 15, quad = lane >> 4;
    const int nTile = blockIdx.x * 128;
    const int mTile = blockIdx.y * 128;

    f32x4 zero = {0.f, 0.f, 0.f, 0.f};
    f32x4 acc[4][4];
    #pragma unroll
    for (int i = 0; i < 4; ++i)
        #pragma unroll
        for (int j = 0; j < 4; ++j) acc[i][j] = zero;

    const int q0 = tid, q1 = tid + 256;
    const int r0 = q0 >> 2, c0 = q0 & 3, ko0 = c0 * 8;
    const int r1 = q1 >> 2, c1 = q1 & 3, ko1 = c1 * 8;
    const int s0 = (r0 << 2) | (c0 ^ ((r0 >> 1) & 3));
    const int s1 = (r1 << 2) | (c1 ^ ((r1 >> 1) & 3));
    const int rsw = quad ^ ((r16 >> 1) & 3);     // read-side swizzled chunk

    const unsigned short* Wp0 = W + (size_t)(nTile + r0) * K + ko0;
    const unsigned short* Wp1 = W + (size_t)(nTile + r1) * K + ko1;
    const unsigned short* Xp0 = X + (size_t)(mTile + r0) * K + ko0;
    const unsigned short* Xp1 = X + (size_t)(mTile + r1) * K + ko1;

    uint4 wv0 = *(const uint4*)(Wp0);
    uint4 wv1 = *(const uint4*)(Wp1);
    uint4 xv0 = *(const uint4*)(Xp0);
    uint4 xv1 = *(const uint4*)(Xp1);

    for (int k0 = 0; k0 < K; k0 += 32) {
        BARRIER_LGKM();                      // prev frag reads done (ds only)
        ((uint4*)sW)[s0] = wv0;
        ((uint4*)sW)[s1] = wv1;
        ((uint4*)sX)[s0] = xv0;
        ((uint4*)sX)[s1] = xv1;
        BARRIER_LGKM();
        if (k0 + 32 < K) {                   // prefetch next K-slice, stays in flight
            wv0 = *(const uint4*)(Wp0 + k0 + 32);
            wv1 = *(const uint4*)(Wp1 + k0 + 32);
            xv0 = *(const uint4*)(Xp0 + k0 + 32);
            xv1 = *(const uint4*)(Xp1 + k0 + 32);
        }
        const bf16x8* sWv = (const bf16x8*)sW;
        const bf16x8* sXv = (const bf16x8*)sX;
        bf16x8 a[4], bx[4];
        #pragma unroll
        for (int i = 0; i < 4; ++i) {
            a[i]  = sWv[((w_n * 64 + i * 16 + r16) << 2) | rsw];
            bx[i] = sXv[((w_m * 64 + i * 16 + r16) << 2) | rsw];
        }
        #pragma unroll
        for (int i = 0; i < 4; ++i)
            #pragma unroll
            for (int j = 0; j < 4; ++j)
                acc[i][j] = __builtin_amdgcn_mfma_f32_16x16x32_bf16(a[i], bx[j], acc[i][j], 0, 0, 0);
    }

    // epilogue: gate-scale + pack; 32B contiguous per (thread, j)
    const int w_idx = ((nTile & 511) >> 6) + w_n;
    const int dirn  = nTile >> 9;
    float4 bv[4];
    #pragma unroll
    for (int i = 0; i < 4; ++i)
        bv[i] = *(const float4*)(bias + nTile + w_n * 64 + i * 16 + quad * 4);
    const int t  = (mTile >> 6) + w_m;           // uniform per thread
    const unsigned pb = (unsigned)(t >> 1) * 131072u + (unsigned)dirn * 65536u
                      + (unsigned)w_idx * 512u + (unsigned)(t & 1) * 256u
                      + (unsigned)quad * 64u;
    #pragma unroll
    for (int j = 0; j < 4; ++j) {
        int b = j * 16 + r16;
        unsigned base = pb + (unsigned)(b >> 2) * 4096u + (unsigned)(b & 3) * 16u;
        ushort4 o[4];
        #pragma unroll
        for (int i = 0; i < 4; ++i) {
            f32x4 v = acc[i][j];
            o[i] = make_ushort4(f2bf((v.x + bv[i].x) * NL2E),
                                f2bf((v.y + bv[i].y) * NL2E),
                                f2bf((v.z + bv[i].z) * N2L2E),
                                f2bf((v.w + bv[i].w) * NL2E));
        }
        uint4 pk0, pk1;
        pk0.x = *(unsigned*)&o[0].x; pk0.y = *((unsigned*)&o[0].x + 1);
        pk0.z = *(unsigned*)&o[1].x; pk0.w = *((unsigned*)&o[1].x + 1);
        pk1.x = *(unsigned*)&o[2].x; pk1.y = *((unsigned*)&o[2].x + 1);
        pk1.z = *(unsigned*)&o[3].x; pk1.w = *((unsigned*)&o[3].x + 1);
        *(uint4*)(xgS + base)     = pk0;
        *(uint4*)(xgS + base + 8) = pk1;
    }
}

// ---------- fp8-MX MFMA LSTM scan: 32 blocks, 512 threads ----------
// exp2-native nonlinearity (scales pre-folded); 32-bit saddr offsets.
__global__ __launch_bounds__(512, 1) void lstm_scan_mfma(
    const unsigned short* __restrict__ xgS,     // scan layout (see gemm)
    const unsigned char* __restrict__ whh_q,    // [2 dir][8 w][4 tile][64 lane][32B] fp8
    unsigned short* __restrict__ xnext)         // [MM][256], col = dir*128 + u
{
    const int dir = blockIdx.x >> 4;
    const int bg  = blockIdx.x & 15;
    const int tid = threadIdx.x;
    const int w   = tid >> 6;
    const int lane= tid & 63;
    const int q   = lane >> 4;
    const int b4  = (lane >> 2) & 3;
    const int d   = lane & 3;
    const int u   = w * 16 + d * 4 + q;      // original unit index this lane owns
    const int b   = bg * 4 + b4;             // batch

    // A-frags: 4 tiles x 32 fp8 bytes per lane (register-resident)
    v8i afrag[4];
    {
        const unsigned char* wb = whh_q + (size_t)dir * 65536 + (size_t)w * 8192 + lane * 32;
        #pragma unroll
        for (int tile = 0; tile < 4; ++tile) {
            uint4 a0 = *(const uint4*)(wb + tile * 2048);
            uint4 a1 = *(const uint4*)(wb + tile * 2048 + 16);
            v8i av; av[0]=a0.x; av[1]=a0.y; av[2]=a0.z; av[3]=a0.w;
                    av[4]=a1.x; av[5]=a1.y; av[6]=a1.z; av[7]=a1.w;
            afrag[tile] = av;
        }
    }

    // h buffers: fp8 bytes, [batch(4) x stride 144][k=unit 0..127], double-buffered
    __shared__ __align__(16) unsigned char hbuf[2][576];
    if (tid < 144) ((unsigned*)hbuf[1])[tid] = 0;    // h(-1) = 0

    const f32x4 zero4 = {0.f, 0.f, 0.f, 0.f};        // loop-invariant MFMA C operand

    float c = 0.f;
    // x offsets: uniform base (1MB-shifted for positive rev prefetch) + 32-bit voffset
    const unsigned short* xb_ptr = xgS + dir * 65536 + bg * 4096 - 524288;
    unsigned xoff = 524288u + (dir ? 255u * 131072u : 0u)
                  + (unsigned)w * 512u + (unsigned)lane * 4u;
    const int pstep = dir ? -131072 : 131072;
    const unsigned tha = dir ? 256u : 0u;            // first substep's thalf slot
    const unsigned thb = dir ? 0u : 256u;

    unsigned short* hb_ptr = xnext + dir * 128;
    unsigned hoff = (dir ? 511u * 16384u : 0u) + (unsigned)b * 256u + (unsigned)u;
    const int hstep = dir ? -16384 : 16384;

    const int hw  = b4 * 144 + u;            // own h byte (write)
    const int hr  = b4 * 144 + q * 32;       // B-frag read base (32 bytes)

    auto step_body = [&](uint2 xv, const unsigned char* rb, unsigned char* wbuf) {
        uint4 h0 = *(const uint4*)(rb + hr);
        uint4 h1 = *(const uint4*)(rb + hr + 16);
        v8i bfr; bfr[0]=h0.x; bfr[1]=h0.y; bfr[2]=h0.z; bfr[3]=h0.w;
                 bfr[4]=h1.x; bfr[5]=h1.y; bfr[6]=h1.z; bfr[7]=h1.w;
        f32x4 a0 = __builtin_amdgcn_mfma_scale_f32_16x16x128_f8f6f4(afrag[0], bfr, zero4, 0, 0,
                       0, 0x79797979, 0, 0x7B7B7B7B);     // A: 2^-6, B: 2^-4
        f32x4 a1 = __builtin_amdgcn_mfma_scale_f32_16x16x128_f8f6f4(afrag[1], bfr, zero4, 0, 0,
                       0, 0x79797979, 0, 0x7B7B7B7B);
        f32x4 a2 = __builtin_amdgcn_mfma_scale_f32_16x16x128_f8f6f4(afrag[2], bfr, zero4, 0, 0,
                       0, 0x79797979, 0, 0x7B7B7B7B);
        f32x4 a3 = __builtin_amdgcn_mfma_scale_f32_16x16x128_f8f6f4(afrag[3], bfr, zero4, 0, 0,
                       0, 0x79797979, 0, 0x7B7B7B7B);
        f32x4 sel = a0;
        sel = (d == 1) ? a1 : sel;
        sel = (d == 2) ? a2 : sel;
        sel = (d == 3) ? a3 : sel;
        // pre-acts already scaled by -log2e (i,f,o) / -2log2e (g)
        float iv = sel.x + bflo(xv.x);
        float fv = sel.y + bfhi(xv.x);
        float gg = sel.z + bflo(xv.y);
        float ov = sel.w + bfhi(xv.y);
        float si = frcp(1.f + exp2f(iv));
        float sf = frcp(1.f + exp2f(fv));
        float so = frcp(1.f + exp2f(ov));
        float tg = 2.f * frcp(1.f + exp2f(gg)) - 1.f;
        c = sf * c + si * tg;
        float tc = 2.f * frcp(1.f + exp2f(N2L2E * c)) - 1.f;
        float h = so * tc;
        hb_ptr[hoff] = f2bf_trunc(h);
        hoff += hstep;
        int q8 = __builtin_amdgcn_cvt_pk_fp8_f32(h * 16.f, h * 16.f, 0, false);
        wbuf[hw] = (unsigned char)(q8 & 0xff);
        BARRIER_LGKM();
    };

    uint2 ringA[4], ringB[4];
    #pragma unroll
    for (int i = 0; i < 4; ++i) {
        ringA[i] = *(const uint2*)(xb_ptr + (xoff + i * pstep + tha));
        ringB[i] = *(const uint2*)(xb_ptr + (xoff + i * pstep + thb));
    }

    BARRIER_LGKM();

    for (int it2 = 0; it2 < 64; ++it2) {
        #pragma unroll
        for (int pp = 0; pp < 4; ++pp) {
            uint2 xa = ringA[pp];
            uint2 xb = ringB[pp];
            ringA[pp] = *(const uint2*)(xb_ptr + (xoff + 4 * pstep + tha));  // pads cover OOB
            ringB[pp] = *(const uint2*)(xb_ptr + (xoff + 4 * pstep + thb));
            xoff += pstep;
            step_body(xa, hbuf[1], hbuf[0]);              // even substep
            step_body(xb, hbuf[0], hbuf[1]);              // odd substep
        }
    }
}

// ---------- emissions: [MM][8] = x2(bf16) @ h2t_w^T + h2t_b (time-major rows) ----------
__global__ void emis_kernel(const unsigned short* __restrict__ x2,
                            const float* __restrict__ h2t_w,
                            const float* __restrict__ h2t_b,
                            float* __restrict__ emis)
{
    int idx = blockIdx.x * 256 + threadIdx.x;   // m*8 + tag
    int m = idx >> 3, tag = idx & 7;
    const unsigned short* xr = x2 + (size_t)m * 256;
    const float* wr = h2t_w + (size_t)tag * 256;
    float a0 = 0.f, a1 = 0.f, a2 = 0.f, a3 = 0.f;
    #pragma unroll 4
    for (int k = 0; k < 256; k += 8) {
        uint4 xv = *(const uint4*)(xr + k);
        float4 w0 = *(const float4*)(wr + k);
        float4 w1 = *(const float4*)(wr + k + 4);
        a0 += bflo(xv.x) * w0.x + bfhi(xv.x) * w0.y;
        a1 += bflo(xv.y) * w0.z + bfhi(xv.y) * w0.w;
        a2 += bflo(xv.z) * w1.x + bfhi(xv.z) * w1.y;
        a3 += bflo(xv.w) * w1.z + bfhi(xv.w) * w1.w;
    }
    emis[idx] = h2t_b[tag] + ((a0 + a1) + (a2 + a3));
}

// ---------- CRF chunk: 8x8 log-semiring product over 64 timesteps ----------
__global__ void crf_chunk(const float* __restrict__ emis,
                          const float* __restrict__ trans,
                          float* __restrict__ Pc)          // [64][8][64]
{
    const int b = blockIdx.x >> 3;
    const int cch = blockIdx.x & 7;
    const int l = threadIdx.x;
    const int i = l >> 3, j = l & 7;
    const int i8 = i * 8;
    float T[8];
    #pragma unroll
    for (int k = 0; k < 8; ++k) T[k] = trans[k * 8 + j];

    const int t0 = (cch == 0) ? 1 : cch * 64;
    const int t1 = cch * 64 + 64;
    const float* ej = emis + (size_t)b * 8 + j;            // e[t] at ej[t*512]

    float P = trans[i * 8 + j] + ej[(size_t)t0 * 512];     // P = M_{t0}
    float e1 = ej[(size_t)(t0 + 1) * 512];
    for (int t = t0 + 1; t < t1; ++t) {
        float v0 = __shfl(P, i8 + 0) + T[0];
        float v1 = __shfl(P, i8 + 1) + T[1];
        float v2 = __shfl(P, i8 + 2) + T[2];
        float v3 = __shfl(P, i8 + 3) + T[3];
        float v4 = __shfl(P, i8 + 4) + T[4];
        float v5 = __shfl(P, i8 + 5) + T[5];
        float v6 = __shfl(P, i8 + 6) + T[6];
        float v7 = __shfl(P, i8 + 7) + T[7];
        float m = fmaxf(fmaxf(fmaxf(v0, v1), fmaxf(v2, v3)),
                        fmaxf(fmaxf(v4, v5), fmaxf(v6, v7)));
        float s = __expf(v0 - m) + __expf(v1 - m) + __expf(v2 - m) + __expf(v3 - m)
                + __expf(v4 - m) + __expf(v5 - m) + __expf(v6 - m) + __expf(v7 - m);
        P = m + __logf(s) + e1;
        e1 = ej[(size_t)(t + 1) * 512];                    // t+1 can hit 512 -> pad
    }
    Pc[((size_t)b * 8 + cch) * 64 + l] = P;
}

// ---------- CRF combine: fv0 o P_0..P_7 + gold score -> atomicAdd into out ----------
__global__ void crf_combine(const float* __restrict__ emis,
                            const float* __restrict__ Pc,     // [64][8][64]
                            const int* __restrict__ tags,
                            const float* __restrict__ trans,
                            float* __restrict__ out)
{
    const int l = threadIdx.x;
    const int sl = l >> 3, j = l & 7, sl8 = sl * 8;
    const int b = blockIdx.x * 8 + sl;

    float fv = emis[(size_t)b * 8 + j];                    // fv0[j] = e[0][j]
    #pragma unroll
    for (int cch = 0; cch < 8; ++cch) {
        const float* Pb = Pc + ((size_t)b * 8 + cch) * 64 + j;
        float p0 = Pb[0],  p1 = Pb[8],  p2 = Pb[16], p3 = Pb[24];
        float p4 = Pb[32], p5 = Pb[40], p6 = Pb[48], p7 = Pb[56];
        float v0 = __shfl(fv, sl8 + 0) + p0;
        float v1 = __shfl(fv, sl8 + 1) + p1;
        float v2 = __shfl(fv, sl8 + 2) + p2;
        float v3 = __shfl(fv, sl8 + 3) + p3;
        float v4 = __shfl(fv, sl8 + 4) + p4;
        float v5 = __shfl(fv, sl8 + 5) + p5;
        float v6 = __shfl(fv, sl8 + 6) + p6;
        float v7 = __shfl(fv, sl8 + 7) + p7;
        float m = fmaxf(fmaxf(fmaxf(v0, v1), fmaxf(v2, v3)),
                        fmaxf(fmaxf(v4, v5), fmaxf(v6, v7)));
        float s = __expf(v0 - m) + __expf(v1 - m) + __expf(v2 - m) + __expf(v3 - m)
                + __expf(v4 - m) + __expf(v5 - m) + __expf(v6 - m) + __expf(v7 - m);
        fv = m + __logf(s);
    }

    float m2 = fv;
    m2 = fmaxf(m2, __shfl_xor(m2, 1));
    m2 = fmaxf(m2, __shfl_xor(m2, 2));
    m2 = fmaxf(m2, __shfl_xor(m2, 4));
    float e2s = __expf(fv - m2);
    e2s += __shfl_xor(e2s, 1);
    e2s += __shfl_xor(e2s, 2);
    e2s += __shfl_xor(e2s, 4);
    float partition = m2 + __logf(e2s);

    const int* tg = tags + (size_t)b * TT;
    float sc = 0.f;
    for (int tt = j; tt < TT; tt += 8) {
        int tag = tg[tt];
        sc += emis[((size_t)tt * 64 + b) * 8 + tag];
        if (tt > 0) sc += trans[tg[tt - 1] * 8 + tag];
    }
    sc += __shfl_xor(sc, 1);
    sc += __shfl_xor(sc, 2);
    sc += __shfl_xor(sc, 4);

    float val = (j == 0) ? (partition - sc) * 0.015625f : 0.f;
    #pragma unroll
    for (int dd = 1; dd < 64; dd <<= 1) val += __shfl_xor(val, dd);
    if (l == 0) atomicAdd(out, val);
}

// ---------- launch ----------
extern "C" void kernel_launch(void* const* d_in, const int* in_sizes, int n_in,
                              void* d_out, int out_size, void* d_ws, size_t ws_size,
                              hipStream_t stream)
{
    const int*   sentences = (const int*)d_in[0];
    const int*   tags      = (const int*)d_in[1];
    const float* embedding = (const float*)d_in[2];
    const float* w_ih_l0   = (const float*)d_in[3];
    const float* w_hh_l0   = (const float*)d_in[4];
    const float* b_ih_l0   = (const float*)d_in[5];
    const float* b_hh_l0   = (const float*)d_in[6];
    const float* w_ih_l0r  = (const float*)d_in[7];
    const float* w_hh_l0r  = (const float*)d_in[8];
    const float* b_ih_l0r  = (const float*)d_in[9];
    const float* b_hh_l0r  = (const float*)d_in[10];
    const float* w_ih_l1   = (const float*)d_in[11];
    const float* w_hh_l1   = (const float*)d_in[12];
    const float* b_ih_l1   = (const float*)d_in[13];
    const float* b_hh_l1   = (const float*)d_in[14];
    const float* w_ih_l1r  = (const float*)d_in[15];
    const float* w_hh_l1r  = (const float*)d_in[16];
    const float* b_ih_l1r  = (const float*)d_in[17];
    const float* b_hh_l1r  = (const float*)d_in[18];
    const float* h2t_w     = (const float*)d_in[19];
    const float* h2t_b     = (const float*)d_in[20];
    const float* trans     = (const float*)d_in[21];

    char* ws = (char*)d_ws;
    unsigned short* W0c   = (unsigned short*)(ws + 0);          //   262,144
    unsigned short* W1c   = (unsigned short*)(ws + 262144);     //   524,288
    int*  Whh0q           = (int*)(ws + 786432);                //   131,072 (fp8)
    int*  Whh1q           = (int*)(ws + 917504);                //   131,072 (fp8)
    float* bias0          = (float*)(ws + 1310720);             //     4,096
    float* bias1          = (float*)(ws + 1314816);             //     4,096
    float* emis           = (float*)(ws + 1318912);             // 1,056,768 (incl pad)
    float* Pc             = (float*)(ws + 2375936);             //   131,072
    unsigned short* xgS   = (unsigned short*)(ws + 4194304);    // 67,108,864 (1MB pads both sides)
    unsigned short* x0    = (unsigned short*)(ws + 71303168);   //  8,388,608 (first 1MB = fwd pad)
    unsigned short* x1    = (unsigned short*)(ws + 72351744);   // 16,777,216
    unsigned short* x2    = x1;                                 // alias (x1 dead after gemm2)
    (void)ws_size; (void)in_sizes; (void)n_in; (void)out_size;

    hipMemsetAsync(d_out, 0, sizeof(float), stream);

    prep_kernel<<<4744, 256, 0, stream>>>(sentences, embedding,
        w_ih_l0, w_ih_l0r, w_ih_l1, w_ih_l1r,
        w_hh_l0, w_hh_l0r, w_hh_l1, w_hh_l1r,
        b_ih_l0, b_hh_l0, b_ih_l0r, b_hh_l0r,
        b_ih_l1, b_hh_l1, b_ih_l1r, b_hh_l1r,
        x0, W0c, W1c, Whh0q, Whh1q, bias0, bias1);

    gemm_xg<<<dim3(8, 256), 256, 0, stream>>>(W0c, x0, bias0, xgS, 128);
    lstm_scan_mfma<<<32, 512, 0, stream>>>(xgS, (const unsigned char*)Whh0q, x1);
    gemm_xg<<<dim3(8, 256), 256, 0, stream>>>(W1c, x1, bias1, xgS, 256);
    lstm_scan_mfma<<<32, 512, 0, stream>>>(xgS, (const unsigned char*)Whh1q, x2);
    emis_kernel<<<1024, 256, 0, stream>>>(x2, h2t_w, h2t_b, emis);
    crf_chunk<<<512, 64, 0, stream>>>(emis, trans, Pc);
    crf_combine<<<8, 64, 0, stream>>>(emis, Pc, tags, trans, (float*)d_out);
}

// Round 8
// 608.933 us; speedup vs baseline: 1.1666x; 1.1666x over previous
//
#include <hip/hip_runtime.h>
#include <cstdint>
#include <cstddef>

// ---------- types / helpers ----------
typedef __attribute__((ext_vector_type(8))) short bf16x8;   // 8 bf16 (MFMA A/B frag)
typedef __attribute__((ext_vector_type(8))) int   v8i;      // 32 fp8 (f8f6f4 A/B frag)
typedef __attribute__((ext_vector_type(4))) float f32x4;    // MFMA C/D frag

__device__ __forceinline__ unsigned short f2bf(float x) {
    union { float f; unsigned u; } v; v.f = x;
    unsigned r = (v.u + 0x7fffu + ((v.u >> 16) & 1u)) >> 16;   // RNE, inputs finite
    return (unsigned short)r;
}
__device__ __forceinline__ unsigned short f2bf_trunc(float x) {
    union { float f; unsigned u; } v; v.f = x;
    return (unsigned short)(v.u >> 16);                        // truncation: 1 inst
}
__device__ __forceinline__ float bflo(unsigned u){ union{unsigned i;float f;}v; v.i = u << 16;        return v.f; }
__device__ __forceinline__ float bfhi(unsigned u){ union{unsigned i;float f;}v; v.i = u & 0xffff0000u; return v.f; }
__device__ __forceinline__ float frcp(float x){ return __builtin_amdgcn_rcpf(x); }
__device__ __forceinline__ float ex2(float x){ return __builtin_amdgcn_exp2f(x); }  // bare v_exp_f32

// lgkm-only barrier: keeps global loads in flight across the sync (CK pattern)
#define BARRIER_LGKM() asm volatile("s_waitcnt lgkmcnt(0)\n\ts_barrier" ::: "memory")

#define BB 64
#define TT 512
#define MM (BB*TT)     // 32768 rows (time-major: m = t*64 + b)
#define NG 1024        // 4H * 2 directions (permuted gate order)

#define NL2E  -1.442695f      // -log2(e): folded into i/f/o gate pre-acts
#define N2L2E -2.885390f      // -2*log2(e): folded into g gate pre-act

// Gate permutation (per direction): g2 = w*64 + tile*16 + uq*4 + gtype
//   unit = w*16 + tile*4 + uq ; orig row = gtype*128 + unit
__device__ __forceinline__ int perm_orig(int g2) {
    return (g2 & 3) * 128 + (g2 >> 6) * 16 + ((g2 >> 4) & 3) * 4 + ((g2 >> 2) & 3);
}

// ---------- prep: gather + permuted weight/bias convert + W_hh fp8 quantize ----------
__global__ void prep_kernel(
    const int* __restrict__ sentences, const float* __restrict__ emb,
    const float* __restrict__ w_ih_l0, const float* __restrict__ w_ih_l0r,
    const float* __restrict__ w_ih_l1, const float* __restrict__ w_ih_l1r,
    const float* __restrict__ w_hh_l0, const float* __restrict__ w_hh_l0r,
    const float* __restrict__ w_hh_l1, const float* __restrict__ w_hh_l1r,
    const float* __restrict__ b_ih_l0, const float* __restrict__ b_hh_l0,
    const float* __restrict__ b_ih_l0r, const float* __restrict__ b_hh_l0r,
    const float* __restrict__ b_ih_l1, const float* __restrict__ b_hh_l1,
    const float* __restrict__ b_ih_l1r, const float* __restrict__ b_hh_l1r,
    unsigned short* __restrict__ x0, unsigned short* __restrict__ W0c,
    unsigned short* __restrict__ W1c,
    int* __restrict__ Whh0q, int* __restrict__ Whh1q,
    float* __restrict__ bias0, float* __restrict__ bias1)
{
    int blk = blockIdx.x;
    if (blk < 4096) {                       // gather: 32768 x 128, time-major rows
        int t4 = blk * 256 + threadIdx.x;
        int e4 = t4 * 4; int m = e4 >> 7; int k = e4 & 127;
        int tt = m >> 6, b = m & 63;
        int s = sentences[b * 512 + tt];
        float4 v = *(const float4*)(emb + (size_t)s * 128 + k);
        *(ushort4*)(x0 + (size_t)m * 128 + k) =
            make_ushort4(f2bf(v.x), f2bf(v.y), f2bf(v.z), f2bf(v.w));
    } else if (blk < 4224) {                // W0c: 1024 x 128, permuted rows (bf16)
        int t4 = (blk - 4096) * 256 + threadIdx.x;
        int e4 = t4 * 4; int n = e4 >> 7; int k = e4 & 127;
        int dir = n >> 9; int orig = perm_orig(n & 511);
        const float* src = dir ? w_ih_l0r : w_ih_l0;
        float4 v = *(const float4*)(src + (size_t)orig * 128 + k);
        *(ushort4*)(W0c + (size_t)n * 128 + k) =
            make_ushort4(f2bf(v.x), f2bf(v.y), f2bf(v.z), f2bf(v.w));
    } else if (blk < 4480) {                // W1c: 1024 x 256, permuted rows (bf16)
        int t4 = (blk - 4224) * 256 + threadIdx.x;
        int e4 = t4 * 4; int n = e4 >> 8; int k = e4 & 255;
        int dir = n >> 9; int orig = perm_orig(n & 511);
        const float* src = dir ? w_ih_l1r : w_ih_l1;
        float4 v = *(const float4*)(src + (size_t)orig * 256 + k);
        *(ushort4*)(W1c + (size_t)n * 256 + k) =
            make_ushort4(f2bf(v.x), f2bf(v.y), f2bf(v.z), f2bf(v.w));
    } else if (blk < 4736) {                // W_hh fp8, A-frag order, -log2e folded
        int lb = blk - 4480;                // 256 blocks: 128 per layer
        int layer = lb >> 7;
        int t4 = (lb & 127) * 256 + threadIdx.x;     // [0, 32768)
        int f  = t4 * 4;                              // byte index in 131072
        int j0   = f & 31;
        int lp   = (f >> 5) & 63;
        int quad = lp >> 4, r = lp & 15;
        int tb   = f >> 11;                           // 0..63
        int tile = tb & 3, w = (tb >> 2) & 7, dir = tb >> 5;
        int g2 = w * 64 + tile * 16 + r;
        int orig = perm_orig(g2);
        const float* src = layer ? (dir ? w_hh_l1r : w_hh_l1)
                                 : (dir ? w_hh_l0r : w_hh_l0);
        int k = quad * 32 + j0;
        // gtype = r & 3 ; g gate gets -2log2e, others -log2e; x64 for fp8 scale 2^-6
        float fac = ((r & 3) == 2) ? (N2L2E * 64.f) : (NL2E * 64.f);
        float4 v = *(const float4*)(src + (size_t)orig * 128 + k);
        int p = __builtin_amdgcn_cvt_pk_fp8_f32(v.x * fac, v.y * fac, 0, false);
        p = __builtin_amdgcn_cvt_pk_fp8_f32(v.z * fac, v.w * fac, p, true);
        (layer ? Whh1q : Whh0q)[f >> 2] = p;
    } else {                                // biases: 2048 values, permuted (unscaled)
        int t = (blk - 4736) * 256 + threadIdx.x;
        int n = t & 1023;
        int dir = n >> 9; int orig = perm_orig(n & 511);
        if (t < 1024)
            bias0[n] = dir ? (b_ih_l0r[orig] + b_hh_l0r[orig]) : (b_ih_l0[orig] + b_hh_l0[orig]);
        else
            bias1[n] = dir ? (b_ih_l1r[orig] + b_hh_l1r[orig]) : (b_ih_l1[orig] + b_hh_l1[orig]);
    }
}

// ---------- GEMM: xg[m][n] = (sum_k X[m][k]*W[n][k] + bias[n]) * gate_fold ----------
// Scan layout (R5-proven): ushort idx = pair*131072 + dir*65536 + bg*4096 + w*512
//                                     + (t&1)... packed per t: lane*8 covers BOTH halves
//   = (t>>1)*131072 + dir*65536 + (b>>2)*4096 + w*512 + (quad*16 + tile*4 + (b&3))*8 + (t&1)*4+gate
__global__ __launch_bounds__(256, 2) void gemm_xg(
    const unsigned short* __restrict__ W,   // [NG][K] permuted rows
    const unsigned short* __restrict__ X,   // [MM][K] time-major
    const float* __restrict__ bias,         // [NG] permuted
    unsigned short* __restrict__ xgS,       // scan layout, 64 MB
    int K)
{
    __shared__ unsigned short sW[128 * 32];
    __shared__ unsigned short sX[128 * 32];
    const int tid  = threadIdx.x;
    const int lane = tid & 63;
    const int wid  = tid >> 6;
    const int w_n  = wid & 1, w_m = wid >> 1;
    const int r16  = lane & 15, quad = lane >> 4;
    const int nTile = blockIdx.x * 128;
    const int mTile = blockIdx.y * 128;

    f32x4 zero = {0.f, 0.f, 0.f, 0.f};
    f32x4 acc[4][4];
    #pragma unroll
    for (int i = 0; i < 4; ++i)
        #pragma unroll
        for (int j = 0; j < 4; ++j) acc[i][j] = zero;

    const int q0 = tid, q1 = tid + 256;
    const int r0 = q0 >> 2, c0 = q0 & 3, ko0 = c0 * 8;
    const int r1 = q1 >> 2, c1 = q1 & 3, ko1 = c1 * 8;
    const int s0 = (r0 << 2) | (c0 ^ ((r0 >> 1) & 3));
    const int s1 = (r1 << 2) | (c1 ^ ((r1 >> 1) & 3));
    const int rsw = quad ^ ((r16 >> 1) & 3);     // read-side swizzled chunk

    const unsigned short* Wp0 = W + (size_t)(nTile + r0) * K + ko0;
    const unsigned short* Wp1 = W + (size_t)(nTile + r1) * K + ko1;
    const unsigned short* Xp0 = X + (size_t)(mTile + r0) * K + ko0;
    const unsigned short* Xp1 = X + (size_t)(mTile + r1) * K + ko1;

    uint4 wv0 = *(const uint4*)(Wp0);
    uint4 wv1 = *(const uint4*)(Wp1);
    uint4 xv0 = *(const uint4*)(Xp0);
    uint4 xv1 = *(const uint4*)(Xp1);

    for (int k0 = 0; k0 < K; k0 += 32) {
        BARRIER_LGKM();                      // prev frag reads done (ds only)
        ((uint4*)sW)[s0] = wv0;
        ((uint4*)sW)[s1] = wv1;
        ((uint4*)sX)[s0] = xv0;
        ((uint4*)sX)[s1] = xv1;
        BARRIER_LGKM();
        if (k0 + 32 < K) {                   // prefetch next K-slice, stays in flight
            wv0 = *(const uint4*)(Wp0 + k0 + 32);
            wv1 = *(const uint4*)(Wp1 + k0 + 32);
            xv0 = *(const uint4*)(Xp0 + k0 + 32);
            xv1 = *(const uint4*)(Xp1 + k0 + 32);
        }
        const bf16x8* sWv = (const bf16x8*)sW;
        const bf16x8* sXv = (const bf16x8*)sX;
        bf16x8 a[4], bx[4];
        #pragma unroll
        for (int i = 0; i < 4; ++i) {
            a[i]  = sWv[((w_n * 64 + i * 16 + r16) << 2) | rsw];
            bx[i] = sXv[((w_m * 64 + i * 16 + r16) << 2) | rsw];
        }
        #pragma unroll
        for (int i = 0; i < 4; ++i)
            #pragma unroll
            for (int j = 0; j < 4; ++j)
                acc[i][j] = __builtin_amdgcn_mfma_f32_16x16x32_bf16(a[i], bx[j], acc[i][j], 0, 0, 0);
    }

    // epilogue: fold gate scales + pack (i/f/g/o of one unit) -> one 8B store
    const int w_idx = ((nTile & 511) >> 6) + w_n;
    const int dirn  = nTile >> 9;
    float4 bv[4];
    #pragma unroll
    for (int i = 0; i < 4; ++i)
        bv[i] = *(const float4*)(bias + nTile + w_n * 64 + i * 16 + quad * 4);
    const int t  = (mTile >> 6) + w_m;
    const size_t pbase = (size_t)(t >> 1) * 131072 + (size_t)dirn * 65536
                       + (size_t)w_idx * 512 + (size_t)(t & 1) * 4;
    #pragma unroll
    for (int j = 0; j < 4; ++j) {
        int b = j * 16 + r16;
        size_t base = pbase + (size_t)(b >> 2) * 4096;
        #pragma unroll
        for (int i = 0; i < 4; ++i) {
            f32x4 v = acc[i][j];
            ushort4 o = make_ushort4(f2bf((v.x + bv[i].x) * NL2E),
                                     f2bf((v.y + bv[i].y) * NL2E),
                                     f2bf((v.z + bv[i].z) * N2L2E),
                                     f2bf((v.w + bv[i].w) * NL2E));
            *(uint2*)(xgS + base + (size_t)(quad * 16 + i * 4 + (b & 3)) * 8) = *(uint2*)&o;
        }
    }
}

// ---------- fp8-MX MFMA LSTM scan: 32 blocks, 512 threads (R5 structure) ----------
// exp2-native nonlinearity (scales pre-folded into W_hh/xg).
__global__ __launch_bounds__(512, 1) void lstm_scan_mfma(
    const unsigned short* __restrict__ xgS,     // [pair][dir][bg][w][lane][8] (bf16)
    const unsigned char* __restrict__ whh_q,    // [2 dir][8 w][4 tile][64 lane][32B] fp8
    unsigned short* __restrict__ xnext)         // [MM][256], col = dir*128 + u
{
    const int dir = blockIdx.x >> 4;
    const int bg  = blockIdx.x & 15;
    const int tid = threadIdx.x;
    const int w   = tid >> 6;
    const int lane= tid & 63;
    const int q   = lane >> 4;
    const int bl  = lane & 15;
    const int d   = bl >> 2;
    const int b4  = bl & 3;
    const int u   = w * 16 + d * 4 + q;      // original unit index this lane owns
    const int b   = bg * 4 + b4;             // batch

    // A-frags: 4 tiles x 32 fp8 bytes per lane (register-resident)
    v8i afrag[4];
    {
        const unsigned char* wb = whh_q + (size_t)dir * 65536 + (size_t)w * 8192 + lane * 32;
        #pragma unroll
        for (int tile = 0; tile < 4; ++tile) {
            uint4 a0 = *(const uint4*)(wb + tile * 2048);
            uint4 a1 = *(const uint4*)(wb + tile * 2048 + 16);
            v8i av; av[0]=a0.x; av[1]=a0.y; av[2]=a0.z; av[3]=a0.w;
                    av[4]=a1.x; av[5]=a1.y; av[6]=a1.z; av[7]=a1.w;
            afrag[tile] = av;
        }
    }

    // h buffers: fp8 bytes, [batch(4) x stride 144][k=unit 0..127], double-buffered
    __shared__ __align__(16) unsigned char hbuf[2][576];
    if (tid < 144) ((unsigned*)hbuf[1])[tid] = 0;    // h(-1) = 0

    float c = 0.f;
    const long pstep = dir ? -131072L : 131072L;        // ushorts per t-PAIR
    const unsigned short* xp = xgS + (size_t)(dir ? 255 : 0) * 131072
                             + (size_t)dir * 65536 + bg * 4096 + w * 512 + lane * 8;
    const long hstep = dir ? -16384L : 16384L;
    long hoff = (long)(dir ? 511 : 0) * 16384 + (long)b * 256 + dir * 128 + u;

    const int hw  = b4 * 144 + u;            // own h byte (write)
    const int hr  = b4 * 144 + q * 32;       // B-frag read base (32 bytes)

    auto step_body = [&](uint2 xv, const unsigned char* rb, unsigned char* wbuf) {
        uint4 h0 = *(const uint4*)(rb + hr);
        uint4 h1 = *(const uint4*)(rb + hr + 16);
        v8i bfr; bfr[0]=h0.x; bfr[1]=h0.y; bfr[2]=h0.z; bfr[3]=h0.w;
                 bfr[4]=h1.x; bfr[5]=h1.y; bfr[6]=h1.z; bfr[7]=h1.w;
        f32x4 gv;
        gv.x = bflo(xv.x); gv.y = bfhi(xv.x);    // i, f (pre-scaled by -log2e)
        gv.z = bflo(xv.y); gv.w = bfhi(xv.y);    // g (-2log2e), o (-log2e)
        f32x4 a0 = gv, a1 = gv, a2 = gv, a3 = gv;
        a0 = __builtin_amdgcn_mfma_scale_f32_16x16x128_f8f6f4(afrag[0], bfr, a0, 0, 0,
                 0, 0x79797979, 0, 0x7B7B7B7B);     // A: 2^-6, B: 2^-4
        a1 = __builtin_amdgcn_mfma_scale_f32_16x16x128_f8f6f4(afrag[1], bfr, a1, 0, 0,
                 0, 0x79797979, 0, 0x7B7B7B7B);
        a2 = __builtin_amdgcn_mfma_scale_f32_16x16x128_f8f6f4(afrag[2], bfr, a2, 0, 0,
                 0, 0x79797979, 0, 0x7B7B7B7B);
        a3 = __builtin_amdgcn_mfma_scale_f32_16x16x128_f8f6f4(afrag[3], bfr, a3, 0, 0,
                 0, 0x79797979, 0, 0x7B7B7B7B);
        f32x4 sel = a0;
        sel = (d == 1) ? a1 : sel;
        sel = (d == 2) ? a2 : sel;
        sel = (d == 3) ? a3 : sel;
        // sigmoid(x) = rcp(1 + 2^(-x*log2e)); tanh(x) = 2*rcp(1 + 2^(-2x*log2e)) - 1
        float si = frcp(1.f + ex2(sel.x));
        float sf = frcp(1.f + ex2(sel.y));
        float tg = 2.f * frcp(1.f + ex2(sel.z)) - 1.f;
        float so = frcp(1.f + ex2(sel.w));
        c = sf * c + si * tg;
        float tc = 2.f * frcp(1.f + ex2(N2L2E * c)) - 1.f;
        float h = so * tc;
        xnext[hoff] = f2bf_trunc(h);
        hoff += hstep;
        int q8 = __builtin_amdgcn_cvt_pk_fp8_f32(h * 16.f, h * 16.f, 0, false);
        wbuf[hw] = (unsigned char)(q8 & 0xff);
        BARRIER_LGKM();
    };

    uint4 ring[4];
    #pragma unroll
    for (int i = 0; i < 4; ++i)
        ring[i] = *(const uint4*)(xp + (long)i * pstep);

    BARRIER_LGKM();

    for (int it2 = 0; it2 < 64; ++it2) {
        #pragma unroll
        for (int pp = 0; pp < 4; ++pp) {
            uint4 rv = ring[pp];
            uint2 xa, xb;
            if (dir) { xa.x = rv.z; xa.y = rv.w; xb.x = rv.x; xb.y = rv.y; }
            else     { xa.x = rv.x; xa.y = rv.y; xb.x = rv.z; xb.y = rv.w; }
            ring[pp] = *(const uint4*)(xp + 4 * pstep);   // prefetch pair+4 (pads cover OOB)
            xp += pstep;
            step_body(xa, hbuf[1], hbuf[0]);              // even substep
            step_body(xb, hbuf[0], hbuf[1]);              // odd substep
        }
    }
}

// ---------- emissions: [MM][8] = x2(bf16) @ h2t_w^T + h2t_b (time-major rows) ----------
__global__ void emis_kernel(const unsigned short* __restrict__ x2,
                            const float* __restrict__ h2t_w,
                            const float* __restrict__ h2t_b,
                            float* __restrict__ emis)
{
    int idx = blockIdx.x * 256 + threadIdx.x;   // m*8 + tag
    int m = idx >> 3, tag = idx & 7;
    const unsigned short* xr = x2 + (size_t)m * 256;
    const float* wr = h2t_w + (size_t)tag * 256;
    float a0 = 0.f, a1 = 0.f, a2 = 0.f, a3 = 0.f;
    #pragma unroll 4
    for (int k = 0; k < 256; k += 8) {
        uint4 xv = *(const uint4*)(xr + k);
        float4 w0 = *(const float4*)(wr + k);
        float4 w1 = *(const float4*)(wr + k + 4);
        a0 += bflo(xv.x) * w0.x + bfhi(xv.x) * w0.y;
        a1 += bflo(xv.y) * w0.z + bfhi(xv.y) * w0.w;
        a2 += bflo(xv.z) * w1.x + bfhi(xv.z) * w1.y;
        a3 += bflo(xv.w) * w1.z + bfhi(xv.w) * w1.w;
    }
    emis[idx] = h2t_b[tag] + ((a0 + a1) + (a2 + a3));
}

// ---------- CRF chunk: 8x8 log-semiring product over 64 timesteps ----------
__global__ void crf_chunk(const float* __restrict__ emis,
                          const float* __restrict__ trans,
                          float* __restrict__ Pc)          // [64][8][64]
{
    const int b = blockIdx.x >> 3;
    const int cch = blockIdx.x & 7;
    const int l = threadIdx.x;
    const int i = l >> 3, j = l & 7;
    const int i8 = i * 8;
    float T[8];
    #pragma unroll
    for (int k = 0; k < 8; ++k) T[k] = trans[k * 8 + j];

    const int t0 = (cch == 0) ? 1 : cch * 64;
    const int t1 = cch * 64 + 64;
    const float* ej = emis + (size_t)b * 8 + j;            // e[t] at ej[t*512]

    float P = trans[i * 8 + j] + ej[(size_t)t0 * 512];     // P = M_{t0}
    float e1 = ej[(size_t)(t0 + 1) * 512];
    for (int t = t0 + 1; t < t1; ++t) {
        float v0 = __shfl(P, i8 + 0) + T[0];
        float v1 = __shfl(P, i8 + 1) + T[1];
        float v2 = __shfl(P, i8 + 2) + T[2];
        float v3 = __shfl(P, i8 + 3) + T[3];
        float v4 = __shfl(P, i8 + 4) + T[4];
        float v5 = __shfl(P, i8 + 5) + T[5];
        float v6 = __shfl(P, i8 + 6) + T[6];
        float v7 = __shfl(P, i8 + 7) + T[7];
        float m = fmaxf(fmaxf(fmaxf(v0, v1), fmaxf(v2, v3)),
                        fmaxf(fmaxf(v4, v5), fmaxf(v6, v7)));
        float s = __expf(v0 - m) + __expf(v1 - m) + __expf(v2 - m) + __expf(v3 - m)
                + __expf(v4 - m) + __expf(v5 - m) + __expf(v6 - m) + __expf(v7 - m);
        P = m + __logf(s) + e1;
        e1 = ej[(size_t)(t + 1) * 512];                    // t+1 can hit 512 -> pad
    }
    Pc[((size_t)b * 8 + cch) * 64 + l] = P;
}

// ---------- CRF combine: fv0 o P_0..P_7 + gold score -> atomicAdd into out ----------
__global__ void crf_combine(const float* __restrict__ emis,
                            const float* __restrict__ Pc,     // [64][8][64]
                            const int* __restrict__ tags,
                            const float* __restrict__ trans,
                            float* __restrict__ out)
{
    const int l = threadIdx.x;
    const int sl = l >> 3, j = l & 7, sl8 = sl * 8;
    const int b = blockIdx.x * 8 + sl;

    float fv = emis[(size_t)b * 8 + j];                    // fv0[j] = e[0][j]
    #pragma unroll
    for (int cch = 0; cch < 8; ++cch) {
        const float* Pb = Pc + ((size_t)b * 8 + cch) * 64 + j;
        float p0 = Pb[0],  p1 = Pb[8],  p2 = Pb[16], p3 = Pb[24];
        float p4 = Pb[32], p5 = Pb[40], p6 = Pb[48], p7 = Pb[56];
        float v0 = __shfl(fv, sl8 + 0) + p0;
        float v1 = __shfl(fv, sl8 + 1) + p1;
        float v2 = __shfl(fv, sl8 + 2) + p2;
        float v3 = __shfl(fv, sl8 + 3) + p3;
        float v4 = __shfl(fv, sl8 + 4) + p4;
        float v5 = __shfl(fv, sl8 + 5) + p5;
        float v6 = __shfl(fv, sl8 + 6) + p6;
        float v7 = __shfl(fv, sl8 + 7) + p7;
        float m = fmaxf(fmaxf(fmaxf(v0, v1), fmaxf(v2, v3)),
                        fmaxf(fmaxf(v4, v5), fmaxf(v6, v7)));
        float s = __expf(v0 - m) + __expf(v1 - m) + __expf(v2 - m) + __expf(v3 - m)
                + __expf(v4 - m) + __expf(v5 - m) + __expf(v6 - m) + __expf(v7 - m);
        fv = m + __logf(s);
    }

    float m2 = fv;
    m2 = fmaxf(m2, __shfl_xor(m2, 1));
    m2 = fmaxf(m2, __shfl_xor(m2, 2));
    m2 = fmaxf(m2, __shfl_xor(m2, 4));
    float e2s = __expf(fv - m2);
    e2s += __shfl_xor(e2s, 1);
    e2s += __shfl_xor(e2s, 2);
    e2s += __shfl_xor(e2s, 4);
    float partition = m2 + __logf(e2s);

    const int* tg = tags + (size_t)b * TT;
    float sc = 0.f;
    for (int tt = j; tt < TT; tt += 8) {
        int tag = tg[tt];
        sc += emis[((size_t)tt * 64 + b) * 8 + tag];
        if (tt > 0) sc += trans[tg[tt - 1] * 8 + tag];
    }
    sc += __shfl_xor(sc, 1);
    sc += __shfl_xor(sc, 2);
    sc += __shfl_xor(sc, 4);

    float val = (j == 0) ? (partition - sc) * 0.015625f : 0.f;
    #pragma unroll
    for (int dd = 1; dd < 64; dd <<= 1) val += __shfl_xor(val, dd);
    if (l == 0) atomicAdd(out, val);
}

// ---------- launch ----------
extern "C" void kernel_launch(void* const* d_in, const int* in_sizes, int n_in,
                              void* d_out, int out_size, void* d_ws, size_t ws_size,
                              hipStream_t stream)
{
    const int*   sentences = (const int*)d_in[0];
    const int*   tags      = (const int*)d_in[1];
    const float* embedding = (const float*)d_in[2];
    const float* w_ih_l0   = (const float*)d_in[3];
    const float* w_hh_l0   = (const float*)d_in[4];
    const float* b_ih_l0   = (const float*)d_in[5];
    const float* b_hh_l0   = (const float*)d_in[6];
    const float* w_ih_l0r  = (const float*)d_in[7];
    const float* w_hh_l0r  = (const float*)d_in[8];
    const float* b_ih_l0r  = (const float*)d_in[9];
    const float* b_hh_l0r  = (const float*)d_in[10];
    const float* w_ih_l1   = (const float*)d_in[11];
    const float* w_hh_l1   = (const float*)d_in[12];
    const float* b_ih_l1   = (const float*)d_in[13];
    const float* b_hh_l1   = (const float*)d_in[14];
    const float* w_ih_l1r  = (const float*)d_in[15];
    const float* w_hh_l1r  = (const float*)d_in[16];
    const float* b_ih_l1r  = (const float*)d_in[17];
    const float* b_hh_l1r  = (const float*)d_in[18];
    const float* h2t_w     = (const float*)d_in[19];
    const float* h2t_b     = (const float*)d_in[20];
    const float* trans     = (const float*)d_in[21];

    char* ws = (char*)d_ws;
    unsigned short* W0c   = (unsigned short*)(ws + 0);          //   262,144
    unsigned short* W1c   = (unsigned short*)(ws + 262144);     //   524,288
    int*  Whh0q           = (int*)(ws + 786432);                //   131,072 (fp8)
    int*  Whh1q           = (int*)(ws + 917504);                //   131,072 (fp8)
    float* bias0          = (float*)(ws + 1310720);             //     4,096
    float* bias1          = (float*)(ws + 1314816);             //     4,096
    float* emis           = (float*)(ws + 1318912);             // 1,056,768 (incl pad)
    float* Pc             = (float*)(ws + 2375936);             //   131,072
    unsigned short* xgS   = (unsigned short*)(ws + 4194304);    // 67,108,864 (1MB pads both sides)
    unsigned short* x0    = (unsigned short*)(ws + 71303168);   //  8,388,608 (first 1MB = fwd pad)
    unsigned short* x1    = (unsigned short*)(ws + 72351744);   // 16,777,216
    unsigned short* x2    = x1;                                 // alias (x1 dead after gemm2)
    (void)ws_size; (void)in_sizes; (void)n_in; (void)out_size;

    hipMemsetAsync(d_out, 0, sizeof(float), stream);

    prep_kernel<<<4744, 256, 0, stream>>>(sentences, embedding,
        w_ih_l0, w_ih_l0r, w_ih_l1, w_ih_l1r,
        w_hh_l0, w_hh_l0r, w_hh_l1, w_hh_l1r,
        b_ih_l0, b_hh_l0, b_ih_l0r, b_hh_l0r,
        b_ih_l1, b_hh_l1, b_ih_l1r, b_hh_l1r,
        x0, W0c, W1c, Whh0q, Whh1q, bias0, bias1);

    gemm_xg<<<dim3(8, 256), 256, 0, stream>>>(W0c, x0, bias0, xgS, 128);
    lstm_scan_mfma<<<32, 512, 0, stream>>>(xgS, (const unsigned char*)Whh0q, x1);
    gemm_xg<<<dim3(8, 256), 256, 0, stream>>>(W1c, x1, bias1, xgS, 256);
    lstm_scan_mfma<<<32, 512, 0, stream>>>(xgS, (const unsigned char*)Whh1q, x2);
    emis_kernel<<<1024, 256, 0, stream>>>(x2, h2t_w, h2t_b, emis);
    crf_chunk<<<512, 64, 0, stream>>>(emis, trans, Pc);
    crf_combine<<<8, 64, 0, stream>>>(emis, Pc, tags, trans, (float*)d_out);
}